// Round 5
// baseline (1108.541 us; speedup 1.0000x reference)
//
#include <hip/hip_runtime.h>
#include <cstddef>
#include <cstdint>

#define B_ 512
#define T_ 2048
#define I_ 16
#define H_ 40

typedef __fp16 half_t;  // matches __builtin_amdgcn_* vector element type exactly
typedef half_t h2 __attribute__((ext_vector_type(2)));
typedef half_t h8 __attribute__((ext_vector_type(8)));

// tanh(x) = 1 - 2/(exp(2x)+1); exp(2x) = exp2(x * 2*log2(e)).
__device__ __forceinline__ float fast_tanh(float x) {
  float e = __builtin_amdgcn_exp2f(x * 2.8853900817779268f);
  return 1.0f - 2.0f * __builtin_amdgcn_rcpf(e + 1.0f);
}

// v_dot2_f32_f16: 2 fp16 MACs with f32 accumulate in one VALU op.
__device__ __forceinline__ float dot2(h2 a, h2 b, float c) {
#if __has_builtin(__builtin_amdgcn_fdot2)
  return __builtin_amdgcn_fdot2(a, b, c, false);
#else
  return c + (float)a[0] * (float)b[0] + (float)a[1] * (float)b[1];
#endif
}

__device__ __forceinline__ h2 pack2(float lo, float hi) {
#if __has_builtin(__builtin_amdgcn_cvt_pkrtz)
  return __builtin_amdgcn_cvt_pkrtz(lo, hi);
#else
  h2 r; r[0] = (half_t)lo; r[1] = (half_t)hi; return r;
#endif
}

#define PIN(v) asm volatile("" : "+v"(v))

// Pack one f32 weight row (stride STR, N2 half2 pairs) into resident half2 VGPRs.
#define LOADW(DST, SRC, STR, N2)                                    \
  _Pragma("unroll") for (int k = 0; k < (N2); ++k) {                \
    DST[k][0] = (half_t)SRC[jr * (STR) + 2 * k];                    \
    DST[k][1] = (half_t)SRC[jr * (STR) + 2 * k + 1];                \
    PIN(DST[k]);                                                    \
  }

// 40-wide dot of preloaded h8 block Q[5] against weight h2 array W[20],
// into 4 named accumulators. h2 extracts are register-pair aligned.
#define HD4(Q, W, A0, A1, A2, A3)                                   \
  _Pragma("unroll") for (int m = 0; m < 5; ++m) {                   \
    h2 p0 = {Q[m][0], Q[m][1]}, p1 = {Q[m][2], Q[m][3]};            \
    h2 p2 = {Q[m][4], Q[m][5]}, p3 = {Q[m][6], Q[m][7]};            \
    A0 = dot2(p0, (W)[4 * m + 0], A0);                              \
    A1 = dot2(p1, (W)[4 * m + 1], A1);                              \
    A2 = dot2(p2, (W)[4 * m + 2], A2);                              \
    A3 = dot2(p3, (W)[4 * m + 3], A3);                              \
  }

// One skewed tick: computes h0[u] (D0), h1[u-1] (D1), h2[u-2] (D2).
// All three depend ONLY on prev-tick h values: read everything first
// (one batched LDS latency), compute 3 independent dot+tanh chains,
// write at the end. Same-wave DS ops are in-order -> next tick's reads
// see these writes without a barrier.
#define TICK(D0, D1, D2, XH) do {                                   \
  h8 q0[5], q1[5], q2[5];                                           \
  if (D0 || D1) { _Pragma("unroll") for (int m = 0; m < 5; ++m)     \
      q0[m] = ((const h8*)&hb16[0][0])[m]; }                        \
  if (D1 || D2) { _Pragma("unroll") for (int m = 0; m < 5; ++m)     \
      q1[m] = ((const h8*)&hb16[1][0])[m]; }                        \
  if (D2)       { _Pragma("unroll") for (int m = 0; m < 5; ++m)     \
      q2[m] = ((const h8*)&hb16[2][0])[m]; }                        \
  float a0=0.f,a1=0.f,a2=0.f,a3=0.f;                                \
  float b0=0.f,b1=0.f,b2=0.f,b3=0.f;                                \
  float c0=0.f,c1=0.f,c2=0.f,c3=0.f;                                \
  float nh0=0.f, nh1=0.f;                                           \
  if (D0) {                                                         \
    a0 = bias0;                                                     \
    a0=dot2(XH[0],w0i[0],a0); a1=dot2(XH[1],w0i[1],a1);             \
    a2=dot2(XH[2],w0i[2],a2); a3=dot2(XH[3],w0i[3],a3);             \
    a0=dot2(XH[4],w0i[4],a0); a1=dot2(XH[5],w0i[5],a1);             \
    a2=dot2(XH[6],w0i[6],a2); a3=dot2(XH[7],w0i[7],a3);             \
    HD4(q0, w0h, a0,a1,a2,a3)   /* h0[u-1] */                       \
  }                                                                 \
  if (D1) {                                                         \
    b0 = bias1;                                                     \
    HD4(q0, w1i, b0,b1,b2,b3)   /* h0[u-1] */                       \
    HD4(q1, w1h, b0,b1,b2,b3)   /* h1[u-2] */                       \
  }                                                                 \
  if (D2) {                                                         \
    c0 = bias2;                                                     \
    HD4(q1, w2i, c0,c1,c2,c3)   /* h1[u-2] */                       \
    HD4(q2, w2h, c0,c1,c2,c3)   /* h2[u-3] */                       \
  }                                                                 \
  if (D0) nh0  = fast_tanh((a0 + a1) + (a2 + a3));                  \
  if (D1) nh1  = fast_tanh((b0 + b1) + (b2 + b3));                  \
  if (D2) nh2v = fast_tanh((c0 + c1) + (c2 + c3));                  \
  if (D0) hb16[0][j] = (half_t)nh0;                                 \
  if (D1) hb16[1][j] = (half_t)nh1;                                 \
  if (D2) hb16[2][j] = (half_t)nh2v;                                \
} while (0)

__device__ __forceinline__ void loadx(h2* xh, const float* __restrict__ p) {
  float4 f0 = ((const float4*)p)[0];
  float4 f1 = ((const float4*)p)[1];
  float4 f2 = ((const float4*)p)[2];
  float4 f3 = ((const float4*)p)[3];
  xh[0] = pack2(f0.x, f0.y); xh[1] = pack2(f0.z, f0.w);
  xh[2] = pack2(f1.x, f1.y); xh[3] = pack2(f1.z, f1.w);
  xh[4] = pack2(f2.x, f2.y); xh[5] = pack2(f2.z, f2.w);
  xh[6] = pack2(f3.x, f3.y); xh[7] = pack2(f3.z, f3.w);
}

__global__ __launch_bounds__(64)
__attribute__((amdgpu_waves_per_eu(1, 1)))  // full 512-reg budget (r4: confirmed effective, 132 VGPR)
void rnn3_fused(const float* __restrict__ x,
                const float* __restrict__ wih0, const float* __restrict__ whh0,
                const float* __restrict__ bih0, const float* __restrict__ bhh0,
                const float* __restrict__ wih1, const float* __restrict__ whh1,
                const float* __restrict__ b_ih1, const float* __restrict__ bhh1,
                const float* __restrict__ wih2, const float* __restrict__ whh2,
                const float* __restrict__ bih2, const float* __restrict__ bhh2,
                const float* __restrict__ fcw, const float* __restrict__ fcb,
                float* __restrict__ out) {
  const int b = blockIdx.x;
  const int j = threadIdx.x;               // lane = hidden unit (j < 40 real)
  const int jr = (j < H_) ? j : (H_ - 1);  // lanes 40..63 duplicate unit 39

  // ---- weights packed fp16: 108 resident VGPRs/lane ----
  h2 w0i[I_ / 2], w0h[H_ / 2], w1i[H_ / 2], w1h[H_ / 2], w2i[H_ / 2], w2h[H_ / 2];
  LOADW(w0i, wih0, I_, I_ / 2)
  LOADW(w0h, whh0, H_, H_ / 2)
  LOADW(w1i, wih1, H_, H_ / 2)
  LOADW(w1h, whh1, H_, H_ / 2)
  LOADW(w2i, wih2, H_, H_ / 2)
  LOADW(w2h, whh2, H_, H_ / 2)

  float bias0 = bih0[jr] + bhh0[jr];  PIN(bias0);
  float bias1 = b_ih1[jr] + bhh1[jr]; PIN(bias1);
  float bias2 = bih2[jr] + bhh2[jr];  PIN(bias2);

  // h broadcast in fp16: uniform 16B reads = 5 reads per 40-vector, conflict-free.
  __shared__ __align__(16) half_t hb16[3][64];
  hb16[0][j] = (half_t)0.f; hb16[1][j] = (half_t)0.f; hb16[2][j] = (half_t)0.f;
  __syncthreads();

  const float* __restrict__ xb = x + (size_t)b * (T_ * I_);

  // x wave-uniform; packed fp16; 2-buffer / distance-2 prefetch.
  h2 xA[8], xB[8];
  loadx(xA, xb);        // x[0]
  loadx(xB, xb + I_);   // x[1]

  float nh2v = 0.f;

  // ---- skewed pipeline: tick u computes h0[u], h1[u-1], h2[u-2] ----
  TICK(1, 0, 0, xA);  loadx(xA, xb + 2 * I_);   // tick 0
  TICK(1, 1, 0, xB);  loadx(xB, xb + 3 * I_);   // tick 1

  for (int u = 2; u < T_; u += 2) {             // ticks 2 .. T-1 (2046, even)
    TICK(1, 1, 1, xA);
    { const int tf = (u + 2 < T_) ? u + 2 : T_ - 1; loadx(xA, xb + (size_t)tf * I_); }
    TICK(1, 1, 1, xB);
    { const int tf = (u + 3 < T_) ? u + 3 : T_ - 1; loadx(xB, xb + (size_t)tf * I_); }
  }

  TICK(0, 1, 1, xA);  // tick T:   h1[T-1], h2[T-2]
  TICK(0, 0, 1, xA);  // tick T+1: h2[T-1]  -> nh2v

  // ---- FC head: out[b] = sum_j fc_w[j]*h2[j] + fc_b ----
  const float fw = (j < H_) ? fcw[j] : 0.f;  // dup lanes (40..63) contribute 0
  float v = nh2v * fw;
#pragma unroll
  for (int off = 32; off > 0; off >>= 1) v += __shfl_down(v, off);
  if (j == 0) out[b] = v + fcb[0];
}

extern "C" void kernel_launch(void* const* d_in, const int* in_sizes, int n_in,
                              void* d_out, int out_size, void* d_ws, size_t ws_size,
                              hipStream_t stream) {
  (void)in_sizes; (void)n_in; (void)d_ws; (void)ws_size; (void)out_size;
  const float* x    = (const float*)d_in[0];
  const float* wih0 = (const float*)d_in[1];
  const float* whh0 = (const float*)d_in[2];
  const float* bih0 = (const float*)d_in[3];
  const float* bhh0 = (const float*)d_in[4];
  const float* wih1 = (const float*)d_in[5];
  const float* whh1 = (const float*)d_in[6];
  const float* bih1 = (const float*)d_in[7];
  const float* bhh1 = (const float*)d_in[8];
  const float* wih2 = (const float*)d_in[9];
  const float* whh2 = (const float*)d_in[10];
  const float* bih2 = (const float*)d_in[11];
  const float* bhh2 = (const float*)d_in[12];
  const float* fcw  = (const float*)d_in[13];
  const float* fcb  = (const float*)d_in[14];
  float* out = (float*)d_out;

  hipLaunchKernelGGL(rnn3_fused, dim3(B_), dim3(64), 0, stream,
                     x, wih0, whh0, bih0, bhh0,
                     wih1, whh1, bih1, bhh1,
                     wih2, whh2, bih2, bhh2,
                     fcw, fcb, out);
}